// Round 1
// baseline (840.379 us; speedup 1.0000x reference)
//
#include <hip/hip_runtime.h>

#define TOKENS 4096
#define DDIM 1024
#define HDIM 4096
#define EDIM 1024
#define NEXP 8
#define SLOTS (TOKENS * 2)               // every token -> exactly 2 slots
#define OUT_MAIN ((size_t)TOKENS * EDIM) // 4,194,304 floats, then 17-elem tail

typedef __bf16 bf16_t;
typedef bf16_t bf16x8 __attribute__((ext_vector_type(8)));
typedef float f32x4 __attribute__((ext_vector_type(4)));

__device__ __forceinline__ unsigned short f32_to_bf16(float f) {
  union { float f; unsigned u; } v; v.f = f;
  unsigned r = v.u + 0x7FFFu + ((v.u >> 16) & 1u); // RNE
  return (unsigned short)(r >> 16);
}

__device__ __forceinline__ void gload_lds16(const void* g, void* l) {
  // async global->LDS, 16B/lane; LDS dest is wave-uniform base + lane*16
  __builtin_amdgcn_global_load_lds(
      (__attribute__((address_space(1))) void*)(g),
      (__attribute__((address_space(3))) void*)(l), 16, 0, 0);
}

// ---------------- gating: logits, softmax, top2, stats, x->bf16 -------------
__global__ __launch_bounds__(256) void gate_kernel(
    const float* __restrict__ x, const float* __restrict__ Wg,
    const float* __restrict__ bg, unsigned short* __restrict__ xb,
    int2* __restrict__ tok_e, float2* __restrict__ tok_w,
    int* __restrict__ counts, float* __restrict__ imp_acc) {
  const int wave = threadIdx.x >> 6;
  const int lane = threadIdx.x & 63;
  const int t = blockIdx.x * 4 + wave;
  const float* xr = x + (size_t)t * DDIM;
  unsigned short* xbr = xb + (size_t)t * DDIM;

  float acc[NEXP];
#pragma unroll
  for (int n = 0; n < NEXP; n++) acc[n] = 0.f;

  for (int d = lane; d < DDIM; d += 64) {
    float xv = xr[d];
    xbr[d] = f32_to_bf16(xv);
    const float4* wp = reinterpret_cast<const float4*>(Wg + (size_t)d * NEXP);
    float4 wa = wp[0], wb2 = wp[1];
    acc[0] += xv * wa.x;  acc[1] += xv * wa.y;
    acc[2] += xv * wa.z;  acc[3] += xv * wa.w;
    acc[4] += xv * wb2.x; acc[5] += xv * wb2.y;
    acc[6] += xv * wb2.z; acc[7] += xv * wb2.w;
  }
#pragma unroll
  for (int n = 0; n < NEXP; n++)
#pragma unroll
    for (int m = 32; m > 0; m >>= 1) acc[n] += __shfl_xor(acc[n], m, 64);

  if (lane == 0) {
    float p[NEXP];
    float mx = -1e30f;
#pragma unroll
    for (int n = 0; n < NEXP; n++) { p[n] = acc[n] + bg[n]; mx = fmaxf(mx, p[n]); }
    float s = 0.f;
#pragma unroll
    for (int n = 0; n < NEXP; n++) { p[n] = expf(p[n] - mx); s += p[n]; }
    float inv = 1.f / s;
#pragma unroll
    for (int n = 0; n < NEXP; n++) p[n] *= inv;
    // top-2, lowest index wins ties (matches jax.lax.top_k)
    int e1 = 0; float p1 = p[0];
#pragma unroll
    for (int n = 1; n < NEXP; n++) if (p[n] > p1) { p1 = p[n]; e1 = n; }
    int e2 = (e1 == 0) ? 1 : 0; float p2 = p[e2];
#pragma unroll
    for (int n = 0; n < NEXP; n++) if (n != e1 && p[n] > p2) { p2 = p[n]; e2 = n; }
    float denom = p1 + p2; // L1 norm of gated (always > 0)
    tok_e[t] = make_int2(e1, e2);
    tok_w[t] = make_float2(p1 / denom, p2 / denom);
    atomicAdd(&counts[e1], 1);
    atomicAdd(&counts[e2], 1);
#pragma unroll
    for (int n = 0; n < NEXP; n++) atomicAdd(&imp_acc[n], p[n]);
  }
}

__global__ void scan_kernel(const int* __restrict__ counts, int* __restrict__ offs) {
  if (threadIdx.x == 0) {
    int s = 0;
#pragma unroll
    for (int n = 0; n < NEXP; n++) { offs[n] = s; s += counts[n]; }
    offs[NEXP] = s;
  }
}

__global__ void assign_kernel(const int2* __restrict__ tok_e,
                              const float2* __restrict__ tok_w,
                              const int* __restrict__ offs, int* __restrict__ cursors,
                              int* __restrict__ token_ids, float* __restrict__ slot_w) {
  int t = blockIdx.x * blockDim.x + threadIdx.x;
  if (t >= TOKENS) return;
  int2 e = tok_e[t];
  float2 w = tok_w[t];
  int s0 = offs[e.x] + atomicAdd(&cursors[e.x], 1);
  token_ids[s0] = t; slot_w[s0] = w.x;
  int s1 = offs[e.y] + atomicAdd(&cursors[e.y], 1);
  token_ids[s1] = t; slot_w[s1] = w.y;
}

// ------------- fp32 [NE][R][C] -> bf16 [NE][C][R] (transpose+convert) -------
__global__ __launch_bounds__(256) void transpose_convert_kernel(
    const float* __restrict__ src, unsigned short* __restrict__ dst, int R, int C) {
  __shared__ float tile[32][33];
  const size_t mat = (size_t)R * C;
  const float* s = src + (size_t)blockIdx.z * mat;
  unsigned short* d = dst + (size_t)blockIdx.z * mat;
  int c0 = blockIdx.x * 32, r0 = blockIdx.y * 32;
  int tx = threadIdx.x, ty = threadIdx.y;
#pragma unroll
  for (int i = 0; i < 32; i += 8)
    tile[ty + i][tx] = s[(size_t)(r0 + ty + i) * C + (c0 + tx)];
  __syncthreads();
#pragma unroll
  for (int i = 0; i < 32; i += 8)
    d[(size_t)(c0 + ty + i) * R + (r0 + tx)] = f32_to_bf16(tile[tx][ty + i]);
}

// ---------------- grouped GEMM1: h = relu(x[tok] @ W1[e] + b1[e]) -----------
// A tile: gathered xb rows [128 x 32]; B tile: W1T rows (=H cols) [128 x 32]
__global__ __launch_bounds__(256) void gemm1_kernel(
    const unsigned short* __restrict__ xb, const unsigned short* __restrict__ w1t,
    const float* __restrict__ b1, const int* __restrict__ token_ids,
    const int* __restrict__ offs, unsigned short* __restrict__ h) {
  const int e = blockIdx.z;
  const int off0 = offs[e];
  const int ne = offs[e + 1] - off0;
  const int mt = blockIdx.y;
  if (mt * 128 >= ne) return;
  const int nt = blockIdx.x;

  __shared__ unsigned short As[128 * 32];
  __shared__ unsigned short Bs[128 * 32];

  const int tid = threadIdx.x;
  const int lane = tid & 63;
  const int wave = tid >> 6;
  const int wm = (wave >> 1) * 64;
  const int wn = (wave & 1) * 64;

  // staging map: thread tid -> LDS ushort idx tid*8 == row (tid>>2), k8 ((tid&3)*8)
  const int srow = tid >> 2;
  const int sk = (tid & 3) * 8;
  int lrow0 = mt * 128 + srow;
  int lrow1 = lrow0 + 64;
  int slot0 = off0 + min(lrow0, ne - 1); // clamp: garbage rows masked at store
  int slot1 = off0 + min(lrow1, ne - 1);
  const unsigned short* gA0 = xb + (size_t)token_ids[slot0] * DDIM + sk;
  const unsigned short* gA1 = xb + (size_t)token_ids[slot1] * DDIM + sk;
  const unsigned short* wbase = w1t + (size_t)e * HDIM * DDIM;
  const unsigned short* gB0 = wbase + (size_t)(nt * 128 + srow) * DDIM + sk;
  const unsigned short* gB1 = gB0 + (size_t)64 * DDIM;

  unsigned short* lA = As + wave * 512; // wave-uniform LDS base (lane*16B auto)
  unsigned short* lB = Bs + wave * 512;

  f32x4 acc[4][4];
#pragma unroll
  for (int i = 0; i < 4; i++)
#pragma unroll
    for (int j = 0; j < 4; j++) acc[i][j] = (f32x4)(0.f);

  const int frow = lane & 15;
  const int fk = (lane >> 4) * 8;

  for (int k0 = 0; k0 < DDIM; k0 += 32) {
    __syncthreads(); // prev reads done before overwrite
    gload_lds16(gA0 + k0, lA);
    gload_lds16(gA1 + k0, lA + 2048);
    gload_lds16(gB0 + k0, lB);
    gload_lds16(gB1 + k0, lB + 2048);
    __syncthreads(); // vmcnt drained by barrier
    bf16x8 af[4], bfv[4];
#pragma unroll
    for (int mi = 0; mi < 4; mi++)
      af[mi] = *reinterpret_cast<const bf16x8*>(&As[(wm + mi * 16 + frow) * 32 + fk]);
#pragma unroll
    for (int ni = 0; ni < 4; ni++)
      bfv[ni] = *reinterpret_cast<const bf16x8*>(&Bs[(wn + ni * 16 + frow) * 32 + fk]);
#pragma unroll
    for (int mi = 0; mi < 4; mi++)
#pragma unroll
      for (int ni = 0; ni < 4; ni++)
        acc[mi][ni] = __builtin_amdgcn_mfma_f32_16x16x32_bf16(af[mi], bfv[ni], acc[mi][ni], 0, 0, 0);
  }

  const float* b1e = b1 + (size_t)e * HDIM + nt * 128;
  const int r4 = (lane >> 4) * 4;
  const int cb = lane & 15;
#pragma unroll
  for (int mi = 0; mi < 4; mi++) {
#pragma unroll
    for (int r = 0; r < 4; r++) {
      int grow = mt * 128 + wm + mi * 16 + r4 + r;
      if (grow < ne) {
        unsigned short* hr = h + (size_t)(off0 + grow) * HDIM + nt * 128;
#pragma unroll
        for (int ni = 0; ni < 4; ni++) {
          int col = wn + ni * 16 + cb;
          float v = acc[mi][ni][r] + b1e[col];
          hr[col] = f32_to_bf16(fmaxf(v, 0.f));
        }
      }
    }
  }
}

// --------- grouped GEMM2: out[tok] += w * (h_slot @ W2[e] + b2[e]) ----------
__global__ __launch_bounds__(256) void gemm2_kernel(
    const unsigned short* __restrict__ h, const unsigned short* __restrict__ w2t,
    const float* __restrict__ b2, const int* __restrict__ token_ids,
    const float* __restrict__ slot_w, const int* __restrict__ offs,
    float* __restrict__ out) {
  const int e = blockIdx.z;
  const int off0 = offs[e];
  const int ne = offs[e + 1] - off0;
  const int mt = blockIdx.y;
  if (mt * 128 >= ne) return;
  const int nt = blockIdx.x;

  __shared__ unsigned short As[128 * 32];
  __shared__ unsigned short Bs[128 * 32];

  const int tid = threadIdx.x;
  const int lane = tid & 63;
  const int wave = tid >> 6;
  const int wm = (wave >> 1) * 64;
  const int wn = (wave & 1) * 64;

  const int srow = tid >> 2;
  const int sk = (tid & 3) * 8;
  int lrow0 = mt * 128 + srow;
  int lrow1 = lrow0 + 64;
  int slot0 = off0 + min(lrow0, ne - 1);
  int slot1 = off0 + min(lrow1, ne - 1);
  const unsigned short* gA0 = h + (size_t)slot0 * HDIM + sk;
  const unsigned short* gA1 = h + (size_t)slot1 * HDIM + sk;
  const unsigned short* wbase = w2t + (size_t)e * EDIM * HDIM;
  const unsigned short* gB0 = wbase + (size_t)(nt * 128 + srow) * HDIM + sk;
  const unsigned short* gB1 = gB0 + (size_t)64 * HDIM;

  unsigned short* lA = As + wave * 512;
  unsigned short* lB = Bs + wave * 512;

  f32x4 acc[4][4];
#pragma unroll
  for (int i = 0; i < 4; i++)
#pragma unroll
    for (int j = 0; j < 4; j++) acc[i][j] = (f32x4)(0.f);

  const int frow = lane & 15;
  const int fk = (lane >> 4) * 8;

  for (int k0 = 0; k0 < HDIM; k0 += 32) {
    __syncthreads();
    gload_lds16(gA0 + k0, lA);
    gload_lds16(gA1 + k0, lA + 2048);
    gload_lds16(gB0 + k0, lB);
    gload_lds16(gB1 + k0, lB + 2048);
    __syncthreads();
    bf16x8 af[4], bfv[4];
#pragma unroll
    for (int mi = 0; mi < 4; mi++)
      af[mi] = *reinterpret_cast<const bf16x8*>(&As[(wm + mi * 16 + frow) * 32 + fk]);
#pragma unroll
    for (int ni = 0; ni < 4; ni++)
      bfv[ni] = *reinterpret_cast<const bf16x8*>(&Bs[(wn + ni * 16 + frow) * 32 + fk]);
#pragma unroll
    for (int mi = 0; mi < 4; mi++)
#pragma unroll
      for (int ni = 0; ni < 4; ni++)
        acc[mi][ni] = __builtin_amdgcn_mfma_f32_16x16x32_bf16(af[mi], bfv[ni], acc[mi][ni], 0, 0, 0);
  }

  const float* b2e = b2 + (size_t)e * EDIM + nt * 128;
  const int r4 = (lane >> 4) * 4;
  const int cb = lane & 15;
#pragma unroll
  for (int mi = 0; mi < 4; mi++) {
#pragma unroll
    for (int r = 0; r < 4; r++) {
      int grow = mt * 128 + wm + mi * 16 + r4 + r;
      if (grow < ne) {
        int slot = off0 + grow;
        int tokid = token_ids[slot];
        float wgt = slot_w[slot];
        float* orow = out + (size_t)tokid * EDIM + nt * 128;
#pragma unroll
        for (int ni = 0; ni < 4; ni++) {
          int col = wn + ni * 16 + cb;
          float v = (acc[mi][ni][r] + b2e[col]) * wgt;
          atomicAdd(&orow[col], v);
        }
      }
    }
  }
}

__global__ void stats_kernel(const float* __restrict__ imp_acc,
                             const int* __restrict__ counts,
                             float* __restrict__ tail) {
  if (threadIdx.x == 0 && blockIdx.x == 0) {
    const float inv = 1.f / (float)TOKENS;
    float lb = 0.f;
    for (int n = 0; n < NEXP; n++) {
      float imp = imp_acc[n] * inv;
      float ld = (float)counts[n] * inv;
      lb += imp * ld;
      tail[1 + n] = imp;
      tail[1 + NEXP + n] = ld;
    }
    tail[0] = (float)NEXP * lb;
  }
}

extern "C" void kernel_launch(void* const* d_in, const int* in_sizes, int n_in,
                              void* d_out, int out_size, void* d_ws, size_t ws_size,
                              hipStream_t stream) {
  const float* x  = (const float*)d_in[0];
  const float* Wg = (const float*)d_in[1];
  const float* bg = (const float*)d_in[2];
  const float* W1 = (const float*)d_in[3];
  const float* b1 = (const float*)d_in[4];
  const float* W2 = (const float*)d_in[5];
  const float* b2 = (const float*)d_in[6];
  // d_in[7] = num_experts_per_tok (==2, hardcoded)
  float* out = (float*)d_out;
  char* ws = (char*)d_ws;

  const size_t XB_OFF   = 0;
  const size_t W1T_OFF  = XB_OFF + (size_t)TOKENS * DDIM * 2;
  const size_t W2T_OFF  = W1T_OFF + (size_t)NEXP * DDIM * HDIM * 2;
  const size_t H_OFF    = W2T_OFF + (size_t)NEXP * HDIM * EDIM * 2;
  const size_t TOKE_OFF = H_OFF + (size_t)SLOTS * HDIM * 2;
  const size_t TOKW_OFF = TOKE_OFF + (size_t)TOKENS * sizeof(int2);
  const size_t TID_OFF  = TOKW_OFF + (size_t)TOKENS * sizeof(float2);
  const size_t SLW_OFF  = TID_OFF + (size_t)SLOTS * 4;
  const size_t META_OFF = SLW_OFF + (size_t)SLOTS * 4;
  const size_t WS_NEED  = META_OFF + 64 * 4;
  if (ws_size < WS_NEED) return; // diagnostic: absmax will equal max|ref| (2.359)

  unsigned short* xb   = (unsigned short*)(ws + XB_OFF);
  unsigned short* w1t  = (unsigned short*)(ws + W1T_OFF);
  unsigned short* w2t  = (unsigned short*)(ws + W2T_OFF);
  unsigned short* hbuf = (unsigned short*)(ws + H_OFF);
  int2*   tok_e = (int2*)(ws + TOKE_OFF);
  float2* tok_w = (float2*)(ws + TOKW_OFF);
  int*    tids  = (int*)(ws + TID_OFF);
  float*  slw   = (float*)(ws + SLW_OFF);
  int*    counts  = (int*)(ws + META_OFF);
  int*    cursors = counts + 8;
  float*  imp_acc = (float*)(cursors + 8);
  int*    offs    = (int*)(imp_acc + 8);

  hipMemsetAsync(out, 0, (size_t)out_size * sizeof(float), stream);
  hipMemsetAsync(counts, 0, 24 * 4, stream); // counts + cursors + imp_acc

  gate_kernel<<<TOKENS / 4, 256, 0, stream>>>(x, Wg, bg, xb, tok_e, tok_w, counts, imp_acc);
  scan_kernel<<<1, 64, 0, stream>>>(counts, offs);
  assign_kernel<<<TOKENS / 256, 256, 0, stream>>>(tok_e, tok_w, offs, cursors, tids, slw);
  transpose_convert_kernel<<<dim3(HDIM / 32, DDIM / 32, NEXP), dim3(32, 8), 0, stream>>>(W1, w1t, DDIM, HDIM);
  transpose_convert_kernel<<<dim3(EDIM / 32, HDIM / 32, NEXP), dim3(32, 8), 0, stream>>>(W2, w2t, HDIM, EDIM);
  gemm1_kernel<<<dim3(HDIM / 128, SLOTS / 128, NEXP), 256, 0, stream>>>(xb, w1t, b1, tids, offs, hbuf);
  gemm2_kernel<<<dim3(EDIM / 128, SLOTS / 128, NEXP), 256, 0, stream>>>(hbuf, w2t, b2, tids, slw, offs, out);
  stats_kernel<<<1, 64, 0, stream>>>(imp_acc, counts, out + OUT_MAIN);
}

// Round 2
// 416.274 us; speedup vs baseline: 2.0188x; 2.0188x over previous
//
#include <hip/hip_runtime.h>

#define TOKENS 4096
#define DDIM 1024
#define HDIM 4096
#define EDIM 1024
#define NEXP 8
#define SLOTS (TOKENS * 2)               // every token -> exactly 2 slots
#define OUT_MAIN ((size_t)TOKENS * EDIM) // 4,194,304 floats, then 17-elem tail

typedef __bf16 bf16_t;
typedef bf16_t bf16x8 __attribute__((ext_vector_type(8)));
typedef float f32x4 __attribute__((ext_vector_type(4)));

__device__ __forceinline__ unsigned short f32_to_bf16(float f) {
  union { float f; unsigned u; } v; v.f = f;
  unsigned r = v.u + 0x7FFFu + ((v.u >> 16) & 1u); // RNE
  return (unsigned short)(r >> 16);
}

__device__ __forceinline__ void gload_lds16(const void* g, void* l) {
  // async global->LDS, 16B/lane; LDS dest is wave-uniform base + lane*16
  __builtin_amdgcn_global_load_lds(
      (__attribute__((address_space(1))) void*)(g),
      (__attribute__((address_space(3))) void*)(l), 16, 0, 0);
}

// ------- gating: logits, softmax, top2, x->bf16; NO global atomics ---------
__global__ __launch_bounds__(256) void gate_kernel(
    const float* __restrict__ x, const float* __restrict__ Wg,
    const float* __restrict__ bg, unsigned short* __restrict__ xb,
    int2* __restrict__ tok_e, float2* __restrict__ tok_w,
    float* __restrict__ probs) {
  const int wave = threadIdx.x >> 6;
  const int lane = threadIdx.x & 63;
  const int t = blockIdx.x * 4 + wave;
  const float4* xr = reinterpret_cast<const float4*>(x + (size_t)t * DDIM);
  ushort4* xbr = reinterpret_cast<ushort4*>(xb + (size_t)t * DDIM);

  float acc[NEXP];
#pragma unroll
  for (int n = 0; n < NEXP; n++) acc[n] = 0.f;

#pragma unroll
  for (int i = 0; i < 4; i++) {
    int d4 = lane + 64 * i;       // float4 index; covers d = d4*4 .. d4*4+3
    float4 xv = xr[d4];
    ushort4 o;
    o.x = f32_to_bf16(xv.x); o.y = f32_to_bf16(xv.y);
    o.z = f32_to_bf16(xv.z); o.w = f32_to_bf16(xv.w);
    xbr[d4] = o;
    const float* wrow = Wg + (size_t)d4 * 4 * NEXP;
#pragma unroll
    for (int n = 0; n < NEXP; n++)
      acc[n] += xv.x * wrow[n] + xv.y * wrow[NEXP + n] +
                xv.z * wrow[2 * NEXP + n] + xv.w * wrow[3 * NEXP + n];
  }
#pragma unroll
  for (int n = 0; n < NEXP; n++)
#pragma unroll
    for (int m = 32; m > 0; m >>= 1) acc[n] += __shfl_xor(acc[n], m, 64);

  if (lane == 0) {
    float p[NEXP];
    float mx = -1e30f;
#pragma unroll
    for (int n = 0; n < NEXP; n++) { p[n] = acc[n] + bg[n]; mx = fmaxf(mx, p[n]); }
    float s = 0.f;
#pragma unroll
    for (int n = 0; n < NEXP; n++) { p[n] = expf(p[n] - mx); s += p[n]; }
    float inv = 1.f / s;
#pragma unroll
    for (int n = 0; n < NEXP; n++) { p[n] *= inv; probs[(size_t)t * NEXP + n] = p[n]; }
    // top-2, lowest index wins ties (matches jax.lax.top_k)
    int e1 = 0; float p1 = p[0];
#pragma unroll
    for (int n = 1; n < NEXP; n++) if (p[n] > p1) { p1 = p[n]; e1 = n; }
    int e2 = (e1 == 0) ? 1 : 0; float p2 = p[e2];
#pragma unroll
    for (int n = 0; n < NEXP; n++) if (n != e1 && p[n] > p2) { p2 = p[n]; e2 = n; }
    float denom = p1 + p2; // L1 norm of gated (always > 0)
    tok_e[t] = make_int2(e1, e2);
    tok_w[t] = make_float2(p1 / denom, p2 / denom);
  }
}

// ---- routing: histogram + scan + slot assignment, all LDS atomics ----------
__global__ __launch_bounds__(1024) void route_kernel(
    const int2* __restrict__ tok_e, const float2* __restrict__ tok_w,
    int* __restrict__ offs_g, int* __restrict__ counts_g,
    int* __restrict__ token_ids, float* __restrict__ slot_w) {
  __shared__ int cnt[NEXP];
  __shared__ int offs[NEXP + 1];
  __shared__ int cur[NEXP];
  const int tid = threadIdx.x;
  if (tid < NEXP) cnt[tid] = 0;
  __syncthreads();
  int2 e[4]; float2 w[4];
#pragma unroll
  for (int i = 0; i < 4; i++) {
    int t = tid + 1024 * i;
    e[i] = tok_e[t]; w[i] = tok_w[t];
    atomicAdd(&cnt[e[i].x], 1);
    atomicAdd(&cnt[e[i].y], 1);
  }
  __syncthreads();
  if (tid == 0) {
    int s = 0;
#pragma unroll
    for (int n = 0; n < NEXP; n++) { offs[n] = s; cur[n] = s; s += cnt[n]; }
    offs[NEXP] = s;
  }
  __syncthreads();
  if (tid < NEXP) { offs_g[tid] = offs[tid]; counts_g[tid] = cnt[tid]; }
  if (tid == 0) offs_g[NEXP] = offs[NEXP];
#pragma unroll
  for (int i = 0; i < 4; i++) {
    int t = tid + 1024 * i;
    int s0 = atomicAdd(&cur[e[i].x], 1);
    token_ids[s0] = t; slot_w[s0] = w[i].x;
    int s1 = atomicAdd(&cur[e[i].y], 1);
    token_ids[s1] = t; slot_w[s1] = w[i].y;
  }
}

// ------------- fp32 [NE][R][C] -> bf16 [NE][C][R] (transpose+convert) -------
__global__ __launch_bounds__(256) void transpose_convert_kernel(
    const float* __restrict__ src, unsigned short* __restrict__ dst, int R, int C) {
  __shared__ float tile[32][33];
  const size_t mat = (size_t)R * C;
  const float* s = src + (size_t)blockIdx.z * mat;
  unsigned short* d = dst + (size_t)blockIdx.z * mat;
  int c0 = blockIdx.x * 32, r0 = blockIdx.y * 32;
  int tx = threadIdx.x, ty = threadIdx.y;
#pragma unroll
  for (int i = 0; i < 32; i += 8)
    tile[ty + i][tx] = s[(size_t)(r0 + ty + i) * C + (c0 + tx)];
  __syncthreads();
#pragma unroll
  for (int i = 0; i < 32; i += 8)
    d[(size_t)(c0 + ty + i) * R + (r0 + tx)] = f32_to_bf16(tile[tx][ty + i]);
}

// ---------------- grouped GEMM1: h = relu(x[tok] @ W1[e] + b1[e]) -----------
__global__ __launch_bounds__(256) void gemm1_kernel(
    const unsigned short* __restrict__ xb, const unsigned short* __restrict__ w1t,
    const float* __restrict__ b1, const int* __restrict__ token_ids,
    const int* __restrict__ offs, unsigned short* __restrict__ h) {
  const int e = blockIdx.z;
  const int off0 = offs[e];
  const int ne = offs[e + 1] - off0;
  const int mt = blockIdx.y;
  if (mt * 128 >= ne) return;
  const int nt = blockIdx.x;

  __shared__ unsigned short As[128 * 32];
  __shared__ unsigned short Bs[128 * 32];

  const int tid = threadIdx.x;
  const int lane = tid & 63;
  const int wave = tid >> 6;
  const int wm = (wave >> 1) * 64;
  const int wn = (wave & 1) * 64;

  const int srow = tid >> 2;
  const int sk = (tid & 3) * 8;
  int lrow0 = mt * 128 + srow;
  int lrow1 = lrow0 + 64;
  int slot0 = off0 + min(lrow0, ne - 1); // clamp: garbage rows masked at store
  int slot1 = off0 + min(lrow1, ne - 1);
  const unsigned short* gA0 = xb + (size_t)token_ids[slot0] * DDIM + sk;
  const unsigned short* gA1 = xb + (size_t)token_ids[slot1] * DDIM + sk;
  const unsigned short* wbase = w1t + (size_t)e * HDIM * DDIM;
  const unsigned short* gB0 = wbase + (size_t)(nt * 128 + srow) * DDIM + sk;
  const unsigned short* gB1 = gB0 + (size_t)64 * DDIM;

  unsigned short* lA = As + wave * 512; // wave-uniform LDS base (lane*16B auto)
  unsigned short* lB = Bs + wave * 512;

  f32x4 acc[4][4];
#pragma unroll
  for (int i = 0; i < 4; i++)
#pragma unroll
    for (int j = 0; j < 4; j++) acc[i][j] = (f32x4)(0.f);

  const int frow = lane & 15;
  const int fk = (lane >> 4) * 8;

  for (int k0 = 0; k0 < DDIM; k0 += 32) {
    __syncthreads(); // prev reads done before overwrite
    gload_lds16(gA0 + k0, lA);
    gload_lds16(gA1 + k0, lA + 2048);
    gload_lds16(gB0 + k0, lB);
    gload_lds16(gB1 + k0, lB + 2048);
    __syncthreads(); // vmcnt drained by barrier
    bf16x8 af[4], bfv[4];
#pragma unroll
    for (int mi = 0; mi < 4; mi++)
      af[mi] = *reinterpret_cast<const bf16x8*>(&As[(wm + mi * 16 + frow) * 32 + fk]);
#pragma unroll
    for (int ni = 0; ni < 4; ni++)
      bfv[ni] = *reinterpret_cast<const bf16x8*>(&Bs[(wn + ni * 16 + frow) * 32 + fk]);
#pragma unroll
    for (int mi = 0; mi < 4; mi++)
#pragma unroll
      for (int ni = 0; ni < 4; ni++)
        acc[mi][ni] = __builtin_amdgcn_mfma_f32_16x16x32_bf16(af[mi], bfv[ni], acc[mi][ni], 0, 0, 0);
  }

  const float* b1e = b1 + (size_t)e * HDIM + nt * 128;
  const int r4 = (lane >> 4) * 4;
  const int cb = lane & 15;
#pragma unroll
  for (int mi = 0; mi < 4; mi++) {
#pragma unroll
    for (int r = 0; r < 4; r++) {
      int grow = mt * 128 + wm + mi * 16 + r4 + r;
      if (grow < ne) {
        unsigned short* hr = h + (size_t)(off0 + grow) * HDIM + nt * 128;
#pragma unroll
        for (int ni = 0; ni < 4; ni++) {
          int col = wn + ni * 16 + cb;
          float v = acc[mi][ni][r] + b1e[col];
          hr[col] = f32_to_bf16(fmaxf(v, 0.f));
        }
      }
    }
  }
}

// --------- grouped GEMM2: out[tok] += w * (h_slot @ W2[e] + b2[e]) ----------
__global__ __launch_bounds__(256) void gemm2_kernel(
    const unsigned short* __restrict__ h, const unsigned short* __restrict__ w2t,
    const float* __restrict__ b2, const int* __restrict__ token_ids,
    const float* __restrict__ slot_w, const int* __restrict__ offs,
    float* __restrict__ out) {
  const int e = blockIdx.z;
  const int off0 = offs[e];
  const int ne = offs[e + 1] - off0;
  const int mt = blockIdx.y;
  if (mt * 128 >= ne) return;
  const int nt = blockIdx.x;

  __shared__ unsigned short As[128 * 32];
  __shared__ unsigned short Bs[128 * 32];

  const int tid = threadIdx.x;
  const int lane = tid & 63;
  const int wave = tid >> 6;
  const int wm = (wave >> 1) * 64;
  const int wn = (wave & 1) * 64;

  const int srow = tid >> 2;
  const int sk = (tid & 3) * 8;
  int lrow0 = mt * 128 + srow;
  int lrow1 = lrow0 + 64;
  int slot0 = off0 + min(lrow0, ne - 1);
  int slot1 = off0 + min(lrow1, ne - 1);
  const unsigned short* gA0 = h + (size_t)slot0 * HDIM + sk;
  const unsigned short* gA1 = h + (size_t)slot1 * HDIM + sk;
  const unsigned short* wbase = w2t + (size_t)e * EDIM * HDIM;
  const unsigned short* gB0 = wbase + (size_t)(nt * 128 + srow) * HDIM + sk;
  const unsigned short* gB1 = gB0 + (size_t)64 * HDIM;

  unsigned short* lA = As + wave * 512;
  unsigned short* lB = Bs + wave * 512;

  f32x4 acc[4][4];
#pragma unroll
  for (int i = 0; i < 4; i++)
#pragma unroll
    for (int j = 0; j < 4; j++) acc[i][j] = (f32x4)(0.f);

  const int frow = lane & 15;
  const int fk = (lane >> 4) * 8;

  for (int k0 = 0; k0 < HDIM; k0 += 32) {
    __syncthreads();
    gload_lds16(gA0 + k0, lA);
    gload_lds16(gA1 + k0, lA + 2048);
    gload_lds16(gB0 + k0, lB);
    gload_lds16(gB1 + k0, lB + 2048);
    __syncthreads();
    bf16x8 af[4], bfv[4];
#pragma unroll
    for (int mi = 0; mi < 4; mi++)
      af[mi] = *reinterpret_cast<const bf16x8*>(&As[(wm + mi * 16 + frow) * 32 + fk]);
#pragma unroll
    for (int ni = 0; ni < 4; ni++)
      bfv[ni] = *reinterpret_cast<const bf16x8*>(&Bs[(wn + ni * 16 + frow) * 32 + fk]);
#pragma unroll
    for (int mi = 0; mi < 4; mi++)
#pragma unroll
      for (int ni = 0; ni < 4; ni++)
        acc[mi][ni] = __builtin_amdgcn_mfma_f32_16x16x32_bf16(af[mi], bfv[ni], acc[mi][ni], 0, 0, 0);
  }

  const float* b2e = b2 + (size_t)e * EDIM + nt * 128;
  const int r4 = (lane >> 4) * 4;
  const int cb = lane & 15;
#pragma unroll
  for (int mi = 0; mi < 4; mi++) {
#pragma unroll
    for (int r = 0; r < 4; r++) {
      int grow = mt * 128 + wm + mi * 16 + r4 + r;
      if (grow < ne) {
        int slot = off0 + grow;
        int tokid = token_ids[slot];
        float wgt = slot_w[slot];
        float* orow = out + (size_t)tokid * EDIM + nt * 128;
#pragma unroll
        for (int ni = 0; ni < 4; ni++) {
          int col = wn + ni * 16 + cb;
          float v = (acc[mi][ni][r] + b2e[col]) * wgt;
          atomicAdd(&orow[col], v);
        }
      }
    }
  }
}

// ------------- stats: importance (column sums of probs), load, lb ----------
__global__ __launch_bounds__(512) void stats_kernel(
    const float* __restrict__ probs, const int* __restrict__ counts,
    float* __restrict__ tail) {
  const int wave = threadIdx.x >> 6; // expert index, 8 waves
  const int lane = threadIdx.x & 63;
  float s = 0.f;
  for (int t = lane; t < TOKENS; t += 64) s += probs[(size_t)t * NEXP + wave];
#pragma unroll
  for (int m = 32; m > 0; m >>= 1) s += __shfl_xor(s, m, 64);
  __shared__ float imp_s[NEXP];
  if (lane == 0) imp_s[wave] = s / (float)TOKENS;
  __syncthreads();
  if (threadIdx.x == 0) {
    float lb = 0.f;
#pragma unroll
    for (int n = 0; n < NEXP; n++) {
      float imp = imp_s[n];
      float ld = (float)counts[n] / (float)TOKENS;
      tail[1 + n] = imp;
      tail[1 + NEXP + n] = ld;
      lb += imp * ld;
    }
    tail[0] = (float)NEXP * lb;
  }
}

extern "C" void kernel_launch(void* const* d_in, const int* in_sizes, int n_in,
                              void* d_out, int out_size, void* d_ws, size_t ws_size,
                              hipStream_t stream) {
  const float* x  = (const float*)d_in[0];
  const float* Wg = (const float*)d_in[1];
  const float* bg = (const float*)d_in[2];
  const float* W1 = (const float*)d_in[3];
  const float* b1 = (const float*)d_in[4];
  const float* W2 = (const float*)d_in[5];
  const float* b2 = (const float*)d_in[6];
  // d_in[7] = num_experts_per_tok (==2, hardcoded)
  float* out = (float*)d_out;
  char* ws = (char*)d_ws;

  const size_t XB_OFF   = 0;
  const size_t W1T_OFF  = XB_OFF + (size_t)TOKENS * DDIM * 2;
  const size_t W2T_OFF  = W1T_OFF + (size_t)NEXP * DDIM * HDIM * 2;
  const size_t H_OFF    = W2T_OFF + (size_t)NEXP * HDIM * EDIM * 2;
  const size_t TOKE_OFF = H_OFF + (size_t)SLOTS * HDIM * 2;
  const size_t TOKW_OFF = TOKE_OFF + (size_t)TOKENS * sizeof(int2);
  const size_t TID_OFF  = TOKW_OFF + (size_t)TOKENS * sizeof(float2);
  const size_t SLW_OFF  = TID_OFF + (size_t)SLOTS * 4;
  const size_t PROB_OFF = SLW_OFF + (size_t)SLOTS * 4;
  const size_t META_OFF = PROB_OFF + (size_t)TOKENS * NEXP * 4;
  const size_t WS_NEED  = META_OFF + 64 * 4;
  if (ws_size < WS_NEED) return; // diagnostic: absmax will equal max|ref| (2.359)

  unsigned short* xb   = (unsigned short*)(ws + XB_OFF);
  unsigned short* w1t  = (unsigned short*)(ws + W1T_OFF);
  unsigned short* w2t  = (unsigned short*)(ws + W2T_OFF);
  unsigned short* hbuf = (unsigned short*)(ws + H_OFF);
  int2*   tok_e = (int2*)(ws + TOKE_OFF);
  float2* tok_w = (float2*)(ws + TOKW_OFF);
  int*    tids  = (int*)(ws + TID_OFF);
  float*  slw   = (float*)(ws + SLW_OFF);
  float*  probs = (float*)(ws + PROB_OFF);
  int*    counts = (int*)(ws + META_OFF);
  int*    offs   = counts + 8;

  hipMemsetAsync(out, 0, (size_t)out_size * sizeof(float), stream);

  gate_kernel<<<TOKENS / 4, 256, 0, stream>>>(x, Wg, bg, xb, tok_e, tok_w, probs);
  route_kernel<<<1, 1024, 0, stream>>>(tok_e, tok_w, offs, counts, tids, slw);
  transpose_convert_kernel<<<dim3(HDIM / 32, DDIM / 32, NEXP), dim3(32, 8), 0, stream>>>(W1, w1t, DDIM, HDIM);
  transpose_convert_kernel<<<dim3(EDIM / 32, HDIM / 32, NEXP), dim3(32, 8), 0, stream>>>(W2, w2t, HDIM, EDIM);
  gemm1_kernel<<<dim3(HDIM / 128, SLOTS / 128, NEXP), 256, 0, stream>>>(xb, w1t, b1, tids, offs, hbuf);
  gemm2_kernel<<<dim3(EDIM / 128, SLOTS / 128, NEXP), 256, 0, stream>>>(hbuf, w2t, b2, tids, slw, offs, out);
  stats_kernel<<<1, 512, 0, stream>>>(probs, counts, out + OUT_MAIN);
}